// Round 14
// baseline (206.240 us; speedup 1.0000x reference)
//
#include <hip/hip_runtime.h>
#include <math.h>

typedef __bf16 bf16x8 __attribute__((ext_vector_type(8)));
typedef float f32x4 __attribute__((ext_vector_type(4)));

#define NB 4
#define NT 48
#define NV 32
#define ND 512
#define NH 8
#define NN 1536   // T*V
#define NBN 6144  // B*N
#define L2E 1.44269504f

#define GLOAD_LDS(g, l) \
    __builtin_amdgcn_global_load_lds( \
        (const __attribute__((address_space(1))) void*)(g), \
        (__attribute__((address_space(3))) void*)(l), 16, 0, 0)

// Fragment-linear K layout: kx2[((bh*96 + g)*12 + c)*128 + r*8 + j]
//   = K'[bh][n = g*16+r][k = c*8+j]; c 0..7 content, 8..9 obs-k, 10..11 zero.
// Fragment-linear V layout: vt2[(((bh*4 + dg)*192 + mc)*16 + dr)*8 + j]
//   = V[bh][m = mc*8+j][d = dg*16+dr].

// ---------------------------------------------------------------------------
// prep: conv_h (blocks 0..1535) + weight transpose (1536..1791) +
// kx2 obs/zero chunks (1792..2559).  log2e folded into Wq/bq scale.
// ---------------------------------------------------------------------------
__global__ __launch_bounds__(256) void prep(
    const float* __restrict__ h, const float* __restrict__ obs,
    const float* __restrict__ Wq, const float* __restrict__ Wk,
    const float* __restrict__ Wv, const float* __restrict__ Wo,
    const float* __restrict__ bq, const float* __restrict__ bk,
    const float* __restrict__ bv,
    const float* __restrict__ Wok, const float* __restrict__ bok,
    __bf16* __restrict__ h_bf, __bf16* __restrict__ WcatT,
    __bf16* __restrict__ WoT, float* __restrict__ biascat,
    __bf16* __restrict__ kx2)
{
    __shared__ float ts[64][68];
    const int tid = threadIdx.x;
    const int bx = blockIdx.x;
    if (bx < 1536) {
        int t = bx * 256 + tid;
        const float4* src = (const float4*)h + (size_t)t * 2;
        float4 a = src[0], b = src[1];
        __bf16 r[8] = {(__bf16)a.x, (__bf16)a.y, (__bf16)a.z, (__bf16)a.w,
                       (__bf16)b.x, (__bf16)b.y, (__bf16)b.z, (__bf16)b.w};
        *(uint4*)(h_bf + (size_t)t * 8) = *(uint4*)r;
    } else if (bx < 1792) {
        int bw = bx - 1536;
        const int p = bw >> 6, tile = bw & 63;
        const int k0 = (tile >> 3) * 64, c0 = (tile & 7) * 64;
        const float* W = (p == 0) ? Wq : (p == 1) ? Wk : (p == 2) ? Wv : Wo;
        const float scale = (p == 0) ? 0.125f * L2E : 1.0f;
        #pragma unroll
        for (int i = 0; i < 4; i++) {
            int r = (tid >> 4) + i * 16;
            float4 v = *(const float4*)(W + (size_t)(k0 + r) * 512 + c0 + (tid & 15) * 4);
            *(float4*)&ts[r][(tid & 15) * 4] = v;
        }
        __syncthreads();
        __bf16 tmp[16];
        #pragma unroll
        for (int j = 0; j < 16; j++)
            tmp[j] = (__bf16)(ts[(tid & 3) * 16 + j][tid >> 2] * scale);
        int crow = c0 + (tid >> 2);
        __bf16* dst = (p < 3)
            ? WcatT + ((size_t)(p * 512 + crow)) * 512 + k0 + (tid & 3) * 16
            : WoT   + ((size_t)crow) * 512 + k0 + (tid & 3) * 16;
        *(uint4*)dst = *(uint4*)tmp;
        *(uint4*)(dst + 8) = *(uint4*)(tmp + 8);
        if (p < 3 && k0 == 0 && tid < 64) {
            const float* bb = (p == 0) ? bq : (p == 1) ? bk : bv;
            biascat[p * 512 + c0 + tid] = bb[c0 + tid] * scale;
        }
    } else {
        // kx2 chunks c = 8..11 : obs-k (8,9) and zeros (10,11)
        int t = (bx - 1792) * 256 + tid;         // 0..196607
        int r = t & 15;
        int c = 8 + ((t >> 4) & 3);
        int grow = t >> 6;                       // bh*96 + g, 0..49151
        __bf16* dst = kx2 + ((size_t)grow * 12 + c) * 128 + r * 8;
        if (c < 10) {
            int bh = grow / 96;
            int g = grow - bh * 96;
            int b = bh >> 3, hh = bh & 7;
            int n = g * 16 + r;
            size_t bn = (size_t)b * NN + n;
            float o0 = obs[bn * 2], o1 = obs[bn * 2 + 1];
            int f0 = hh * 16 + (c - 8) * 8;
            __bf16 tmp[8];
            #pragma unroll
            for (int j = 0; j < 8; j++)
                tmp[j] = (__bf16)(o0 * Wok[f0 + j] + o1 * Wok[128 + f0 + j]
                                  + bok[f0 + j]);
            *(uint4*)dst = *(uint4*)tmp;
        } else {
            uint4 z = {0, 0, 0, 0};
            *(uint4*)dst = z;
        }
    }
}

// ---------------------------------------------------------------------------
// bf16 MFMA GEMM — R11-proven structure (BK=32, global_load_lds staging,
// XOR-swizzled LDS, LDS-staged coalesced epilogues). Only the K/V epilogue
// destination math changed (fragment-linear kx2 / vt2).
// ---------------------------------------------------------------------------
template<int TM, bool BF16OUT>
__global__ __launch_bounds__(256) void gemm_mfma(
    const __bf16* __restrict__ A, const __bf16* __restrict__ Bt,
    const float* __restrict__ bias, float* __restrict__ Cf,
    __bf16* __restrict__ qarr, __bf16* __restrict__ kx2,
    __bf16* __restrict__ vt2)
{
    constexpr int MT = TM / 32;
    __shared__ __align__(16) char smem[34816];
    __bf16 (*As)[32] = (__bf16(*)[32])smem;
    __bf16 (*Bs)[32] = (__bf16(*)[32])(smem + TM * 64);
    const int tid = threadIdx.x;
    const int w = tid >> 6, lane = tid & 63;
    const int quad = lane >> 4, l16 = lane & 15;
    const int wm = w >> 1, wn = w & 1;
    const int n0 = blockIdx.x * 128, m0 = blockIdx.y * TM;

    const int sm = tid >> 2;
    const int sk = ((tid & 3) ^ ((sm >> 1) & 3)) * 8;
    const __bf16* aptr = A  + (size_t)(m0 + sm) * 512 + sk;
    const __bf16* bptr = Bt + (size_t)(n0 + sm) * 512 + sk;
    __bf16* lA = (__bf16*)As + tid * 8;
    __bf16* lB = (__bf16*)Bs + tid * 8;

    f32x4 zero4 = {0.f, 0.f, 0.f, 0.f};
    f32x4 acc[MT][4];
    #pragma unroll
    for (int i = 0; i < MT; i++)
        #pragma unroll
        for (int j = 0; j < 4; j++) acc[i][j] = zero4;

    for (int kt = 0; kt < 512; kt += 32) {
        __syncthreads();
        GLOAD_LDS(aptr + kt, lA);
        if (TM == 128) GLOAD_LDS(aptr + 64 * 512 + kt, lA + 2048);
        GLOAD_LDS(bptr + kt, lB);
        GLOAD_LDS(bptr + 64 * 512 + kt, lB + 2048);
        __syncthreads();
        bf16x8 af[MT], bfr[4];
        #pragma unroll
        for (int mt = 0; mt < MT; mt++) {
            int rr = wm * (TM / 2) + mt * 16 + l16;
            af[mt] = *(const bf16x8*)&As[rr][(quad ^ ((rr >> 1) & 3)) * 8];
        }
        #pragma unroll
        for (int nt = 0; nt < 4; nt++) {
            int rr = wn * 64 + nt * 16 + l16;
            bfr[nt] = *(const bf16x8*)&Bs[rr][(quad ^ ((rr >> 1) & 3)) * 8];
        }
        #pragma unroll
        for (int mt = 0; mt < MT; mt++)
            #pragma unroll
            for (int nt = 0; nt < 4; nt++)
                acc[mt][nt] = __builtin_amdgcn_mfma_f32_16x16x32_bf16(
                    af[mt], bfr[nt], acc[mt][nt], 0, 0, 0);
    }

    __syncthreads();   // frag reads done; smem becomes C-stage
    if (BF16OUT) {
        if (n0 >= 1024) {
            // ---- V tile -> vt2 (fragment-linear), staged transposed ----
            __bf16* CsT = (__bf16*)smem;              // [128 cols][136]
            #pragma unroll
            for (int nt = 0; nt < 4; nt++) {
                int cl = wn * 64 + nt * 16 + l16;
                float bia = bias[n0 + cl];
                #pragma unroll
                for (int mt = 0; mt < MT; mt++) {
                    int rl0 = wm * (TM / 2) + mt * 16 + quad * 4;
                    __bf16 pk[4];
                    #pragma unroll
                    for (int r = 0; r < 4; r++)
                        pk[r] = (__bf16)(acc[mt][nt][r] + bia);
                    *(uint2*)&CsT[cl * 136 + rl0] = *(uint2*)pk;
                }
            }
            __syncthreads();
            int cl = tid >> 1, half = tid & 1;
            int f0 = (n0 + cl) & 511;
            int hh = f0 >> 6, d = f0 & 63;
            int bidx = m0 / NN, nm = m0 - bidx * NN;
            size_t vg = ((size_t)(bidx * 8 + hh) * 4 + (d >> 4)) * 192
                      + (nm >> 3) + half * 8;
            __bf16* dst = vt2 + (vg * 16 + (d & 15)) * 8;
            #pragma unroll
            for (int j = 0; j < 8; j++) {
                uint4 v = *(uint4*)&CsT[cl * 136 + half * 64 + j * 8];
                *(uint4*)(dst + (size_t)j * 128) = v;
            }
        } else {
            // ---- Q/K tile: row-major stage, routed stores ----
            __bf16* Cs = (__bf16*)smem;               // [TM][132]
            #pragma unroll
            for (int mt = 0; mt < MT; mt++)
                #pragma unroll
                for (int nt = 0; nt < 4; nt++) {
                    int cl = wn * 64 + nt * 16 + l16;
                    float bia = bias[n0 + cl];
                    #pragma unroll
                    for (int r = 0; r < 4; r++) {
                        int rl = wm * (TM / 2) + mt * 16 + quad * 4 + r;
                        Cs[rl * 132 + cl] = (__bf16)(acc[mt][nt][r] + bia);
                    }
                }
            __syncthreads();
            int rl = tid >> 1, hb = tid & 1;
            int grow = m0 + rl;
            int col0 = n0 + hb * 64;
            int p = col0 >> 9, f0 = col0 & 511, hh = f0 >> 6;
            int bidx = grow / NN, n = grow - bidx * NN;
            if (p == 0) {
                __bf16* dst = qarr + (size_t)grow * 512 + f0;
                #pragma unroll
                for (int j = 0; j < 8; j++) {
                    uint2 lo = *(uint2*)&Cs[rl * 132 + hb * 64 + j * 8];
                    uint2 hi = *(uint2*)&Cs[rl * 132 + hb * 64 + j * 8 + 4];
                    uint4 v = {lo.x, lo.y, hi.x, hi.y};
                    *(uint4*)(dst + j * 8) = v;
                }
            } else {
                // kx2 fragment-linear: chunk j at ((bh96g*12 + j)*128 + r*8)
                size_t bh96g = (size_t)(bidx * 8 + hh) * 96 + (n >> 4);
                __bf16* dst = kx2 + bh96g * 1536 + (n & 15) * 8;
                #pragma unroll
                for (int j = 0; j < 8; j++) {
                    uint2 lo = *(uint2*)&Cs[rl * 132 + hb * 64 + j * 8];
                    uint2 hi = *(uint2*)&Cs[rl * 132 + hb * 64 + j * 8 + 4];
                    uint4 v = {lo.x, lo.y, hi.x, hi.y};
                    *(uint4*)(dst + (size_t)j * 128) = v;
                }
            }
        }
    } else {
        float* Csf = (float*)smem;                // [64][132]
        #pragma unroll
        for (int mt = 0; mt < MT; mt++)
            #pragma unroll
            for (int nt = 0; nt < 4; nt++) {
                int cl = wn * 64 + nt * 16 + l16;
                float bia = bias[n0 + cl];
                #pragma unroll
                for (int r = 0; r < 4; r++) {
                    int rl = wm * (TM / 2) + mt * 16 + quad * 4 + r;
                    Csf[rl * 132 + cl] = acc[mt][nt][r] + bia;
                }
            }
        __syncthreads();
        int rl = tid >> 2, q4 = tid & 3;
        float* dst = Cf + (size_t)(m0 + rl) * 512 + n0 + q4 * 32;
        #pragma unroll
        for (int j = 0; j < 8; j++) {
            uint4 v = *(uint4*)&Csf[rl * 132 + q4 * 32 + j * 4];
            *(uint4*)(dst + j * 4) = v;
        }
    }
}

// ---------------------------------------------------------------------------
// Flash attention, BARRIER-FREE: K and V fragments read directly from global
// in fragment-linear layouts (each operand load = 1 KB/wave fully coalesced,
// L2-hot via the XCD swizzle). LDS = wave-private Ps only (8.2 KB). The
// compiler pipelines loads across tiles with fine-grained vmcnt — no
// convoy drains. Grid (32 bh, 24 qt). Transposed orientation as R11.
// ---------------------------------------------------------------------------
__global__ __launch_bounds__(256) void attn_mfma(
    const __bf16* __restrict__ qarr, const __bf16* __restrict__ kx2,
    const __bf16* __restrict__ vt2, const float* __restrict__ obs,
    const float* __restrict__ Woq, const float* __restrict__ boq,
    const float* __restrict__ varb, const float* __restrict__ rtb,
    __bf16* __restrict__ aout)
{
    __shared__ __align__(16) __bf16 Ps[64][64];   // [n][m] chunk-XOR swizzled

    const int tid = threadIdx.x;
    const int w = tid >> 6, lane = tid & 63;
    const int quad = lane >> 4, l16 = lane & 15;
    const int bh = blockIdx.x, qt = blockIdx.y;   // XCD-locality swizzle
    const int b = bh >> 3, h = bh & 7;
    const int n0 = qt * 64;

    // Q fragments (B-operand): lane l16 holds row n = w*16+l16
    const int nl = w * 16 + l16;
    const size_t qrow = (size_t)(b * NN + n0 + nl);
    bf16x8 bq_[3];
    bq_[0] = *(const bf16x8*)(qarr + qrow * 512 + h * 64 + quad * 8);
    bq_[1] = *(const bf16x8*)(qarr + qrow * 512 + h * 64 + 32 + quad * 8);
    {   // inline oq: logical k 64..95 -> oq[0..15] then zeros; 0.25*log2e folded
        uint4 a2u = {0u, 0u, 0u, 0u};
        if (quad < 2) {
            float o0 = obs[qrow * 2], o1 = obs[qrow * 2 + 1];
            int f = h * 16 + quad * 8;
            const float sc = 0.25f * L2E;
            __bf16 tmp[8];
            #pragma unroll
            for (int j = 0; j < 8; j++)
                tmp[j] = (__bf16)(sc * (o0 * Woq[f + j] + o1 * Woq[128 + f + j]
                                        + boq[f + j]));
            a2u = *(uint4*)tmp;
        }
        bq_[2] = *(bf16x8*)&a2u;
    }

    // var-bias: row (n&31) fixed per lane; m&31 = (ct&1)*16 + quad*4 + r
    const int rm = (w & 1) * 16 + l16;
    float4 vbA = *(const float4*)(varb + h * 1024 + rm * 32 + quad * 4);
    float4 vbB = *(const float4*)(varb + h * 1024 + rm * 32 + 16 + quad * 4);
    float vA[4] = {vbA.x * L2E, vbA.y * L2E, vbA.z * L2E, vbA.w * L2E};
    float vB[4] = {vbB.x * L2E, vbB.y * L2E, vbB.z * L2E, vbB.w * L2E};
    const int tn = 2 * qt + (w >> 1);
    const float* rtbh = rtb + h * 95 + tn + 47;   // wave-uniform

    // direct-global fragment bases (quad/l16 folded in)
    const __bf16* kfb = kx2 + (size_t)bh * 147456 + quad * 128 + l16 * 8;
    const __bf16* vfb = vt2 + (size_t)bh * 98304  + quad * 128 + l16 * 8;

    // Ps chunk-XOR offsets (bytes), precomputed once
    int wo2[4], ro2[2];
    #pragma unroll
    for (int ct = 0; ct < 4; ct++)
        wo2[ct] = (((ct * 2 + (quad >> 1)) ^ (nl & 7)) * 16) + (quad & 1) * 8;
    #pragma unroll
    for (int ks = 0; ks < 2; ks++)
        ro2[ks] = ((ks * 4 + quad) ^ (nl & 7)) * 16;
    char* psrow = (char*)Ps + nl * 128;

    f32x4 zero4 = {0.f, 0.f, 0.f, 0.f};
    f32x4 o[4];
    float lp = 0.f;
    #pragma unroll
    for (int i = 0; i < 4; i++) o[i] = zero4;

    for (int mt = 0; mt < 24; mt++) {
        float tb0 = rtbh[-2 * mt] * L2E;
        float tb1 = rtbh[-2 * mt - 1] * L2E;
        // ---- S^T = K.Q^T over K=96, direct-global K fragments ----
        #pragma unroll
        for (int ct = 0; ct < 4; ct++) {
            f32x4 d = zero4;
            #pragma unroll
            for (int ks = 0; ks < 3; ks++) {
                bf16x8 kf = *(const bf16x8*)(kfb
                    + (((size_t)(mt * 4 + ct) * 12 + ks * 4) << 7));
                d = __builtin_amdgcn_mfma_f32_16x16x32_bf16(kf, bq_[ks], d, 0, 0, 0);
            }
            // softmax for this ct; packed b64 P-store
            float tb = (ct & 2) ? tb1 : tb0;
            const float* vv = (ct & 1) ? vB : vA;
            __bf16 pk[4];
            #pragma unroll
            for (int r = 0; r < 4; r++) {
                float p = exp2f(d[r] + tb + vv[r]);
                lp += p;
                pk[r] = (__bf16)p;
            }
            *(uint2*)(psrow + wo2[ct]) = *(uint2*)pk;
        }
        // ---- O^T += V^T.P^T, direct-global V fragments ----
        #pragma unroll
        for (int ks = 0; ks < 2; ks++) {
            bf16x8 pf = *(const bf16x8*)(psrow + ro2[ks]);
            #pragma unroll
            for (int dt = 0; dt < 4; dt++) {
                bf16x8 vf = *(const bf16x8*)(vfb
                    + (((size_t)dt * 192 + mt * 8 + ks * 4) << 7));
                o[dt] = __builtin_amdgcn_mfma_f32_16x16x32_bf16(vf, pf, o[dt], 0, 0, 0);
            }
        }
    }

    // final l reduction (across quads only) + packed epilogue
    lp += __shfl_xor(lp, 16);
    lp += __shfl_xor(lp, 32);
    float inv = 1.0f / lp;
    size_t abase = ((size_t)b * NN + n0 + nl) * 512 + h * 64 + quad * 4;
    #pragma unroll
    for (int dt = 0; dt < 4; dt++) {
        __bf16 ov[4];
        #pragma unroll
        for (int r = 0; r < 4; r++) ov[r] = (__bf16)(o[dt][r] * inv);
        *(uint2*)(aout + abase + dt * 16) = *(uint2*)ov;
    }
}

extern "C" void kernel_launch(void* const* d_in, const int* in_sizes, int n_in,
                              void* d_out, int out_size, void* d_ws, size_t ws_size,
                              hipStream_t stream)
{
    const float* h_   = (const float*)d_in[0];
    const float* obs  = (const float*)d_in[1];
    const float* Wq   = (const float*)d_in[2];
    const float* bq   = (const float*)d_in[3];
    const float* Wk   = (const float*)d_in[4];
    const float* bk   = (const float*)d_in[5];
    const float* Wv   = (const float*)d_in[6];
    const float* bv   = (const float*)d_in[7];
    const float* Wo   = (const float*)d_in[8];
    const float* bo   = (const float*)d_in[9];
    const float* Woq  = (const float*)d_in[10];
    const float* boq  = (const float*)d_in[11];
    const float* Wok  = (const float*)d_in[12];
    const float* bok  = (const float*)d_in[13];
    const float* varb = (const float*)d_in[14];
    const float* rtb  = (const float*)d_in[15];
    float* out = (float*)d_out;

    char* ws = (char*)d_ws;
    __bf16* h_bf    = (__bf16*)ws;                 ws += (size_t)NBN * 512 * 2;
    __bf16* qarr    = (__bf16*)ws;                 ws += (size_t)NBN * 512 * 2;
    __bf16* vt2     = (__bf16*)ws;                 ws += (size_t)NBN * 512 * 2;
    __bf16* kx2     = (__bf16*)ws;                 ws += (size_t)32 * 96 * 12 * 128 * 2;
    __bf16* attnout = (__bf16*)ws;                 ws += (size_t)NBN * 512 * 2;
    __bf16* WcatT   = (__bf16*)ws;                 ws += (size_t)1536 * 512 * 2;
    __bf16* WoT     = (__bf16*)ws;                 ws += (size_t)512 * 512 * 2;
    float*  biascat = (float*)ws;                  ws += 1536 * 4;

    prep<<<dim3(2560), dim3(256), 0, stream>>>(
        h_, obs, Wq, Wk, Wv, Wo, bq, bk, bv, Wok, bok,
        h_bf, WcatT, WoT, biascat, kx2);
    gemm_mfma<128, true><<<dim3(12, 48), dim3(256), 0, stream>>>(
        h_bf, WcatT, biascat, nullptr, qarr, kx2, vt2);
    attn_mfma<<<dim3(32, 24), dim3(256), 0, stream>>>(qarr, kx2, vt2, obs, Woq, boq,
                                                      varb, rtb, attnout);
    gemm_mfma<64, false><<<dim3(4, 96), dim3(256), 0, stream>>>(
        attnout, WoT, bo, out, nullptr, nullptr, nullptr);
}